// Round 1
// baseline (974.993 us; speedup 1.0000x reference)
//
#include <hip/hip_runtime.h>
#include <hip/hip_bf16.h>

typedef unsigned int u32;
typedef unsigned short u16;

static constexpr int Cn = 96;
static constexpr int HWn = 65536;

__device__ __forceinline__ float bf2f(u16 u) {
    union { u32 i; float f; } z; z.i = ((u32)u) << 16; return z.f;
}
__device__ __forceinline__ u16 f2bf(float f) {
    __hip_bfloat16 h = __float2bfloat16(f);
    return *reinterpret_cast<u16*>(&h);
}
__device__ __forceinline__ float dot2bf(u32 a, u32 b) {
    union { u32 i; float f; } al, ah, bl, bh;
    al.i = a << 16; ah.i = a & 0xffff0000u;
    bl.i = b << 16; bh.i = b & 0xffff0000u;
    return fmaf(al.f, bl.f, ah.f * bh.f);
}
__device__ __forceinline__ float sq2bf(u32 a) {
    union { u32 i; float f; } al, ah;
    al.i = a << 16; ah.i = a & 0xffff0000u;
    return fmaf(al.f, al.f, ah.f * ah.f);
}

// K1: pointwise convs. grid (64 px-tiles, 9 oc-tiles, 4 b). 32 oc x 1024 px per block.
__global__ __launch_bounds__(256) void k_conv1x1_in(
    const float* __restrict__ ff, const float* __restrict__ x,
    const float* __restrict__ w_q, const float* __restrict__ w_kv,
    u16* __restrict__ qpre, u16* __restrict__ kvpre)
{
    const int b = blockIdx.z;
    const int t = blockIdx.y;            // 0..2: q from ff; 3..8: kv from x
    const int tid = threadIdx.x;
    const int p = blockIdx.x * 1024 + tid * 4;

    const float* src; const float* w; u16* dst;
    if (t < 3) {
        src = ff + (size_t)b * Cn * HWn;
        w = w_q + t * 32 * Cn;
        dst = qpre + (size_t)b * Cn * HWn + (size_t)(t * 32) * HWn;
    } else {
        src = x + (size_t)b * Cn * HWn;
        w = w_kv + (t - 3) * 32 * Cn;
        dst = kvpre + (size_t)b * 2 * Cn * HWn + (size_t)((t - 3) * 32) * HWn;
    }

    __shared__ float wt[96 * 32];   // transposed: wt[i][oc]
    for (int idx = tid; idx < 96 * 32; idx += 256) {
        const int oc = idx / 96, i = idx % 96;
        wt[i * 32 + oc] = w[idx];
    }
    __syncthreads();

    float acc[32][4];
    #pragma unroll
    for (int oc = 0; oc < 32; ++oc) { acc[oc][0] = acc[oc][1] = acc[oc][2] = acc[oc][3] = 0.f; }

    for (int i = 0; i < 96; ++i) {
        const float4 v = *reinterpret_cast<const float4*>(src + (size_t)i * HWn + p);
        const float* wr = &wt[i * 32];
        #pragma unroll
        for (int oc = 0; oc < 32; ++oc) {
            const float wv = wr[oc];
            acc[oc][0] = fmaf(wv, v.x, acc[oc][0]);
            acc[oc][1] = fmaf(wv, v.y, acc[oc][1]);
            acc[oc][2] = fmaf(wv, v.z, acc[oc][2]);
            acc[oc][3] = fmaf(wv, v.w, acc[oc][3]);
        }
    }
    #pragma unroll
    for (int oc = 0; oc < 32; ++oc) {
        ushort4 s;
        s.x = f2bf(acc[oc][0]); s.y = f2bf(acc[oc][1]);
        s.z = f2bf(acc[oc][2]); s.w = f2bf(acc[oc][3]);
        *reinterpret_cast<ushort4*>(dst + (size_t)oc * HWn + p) = s;
    }
}

// K2: depthwise 3x3 + on-the-fly reductions (ssq_q, ssq_k, S=q k^T per head) + v store.
// grid (512 row-tiles, 4 b). tile = 128 wide x 1 high. 256 threads: (px 0..127) x (half 0..1).
__global__ __launch_bounds__(256) void k_dw_reduce(
    const u16* __restrict__ qpre, const u16* __restrict__ kvpre,
    const float* __restrict__ wqdw, const float* __restrict__ wkvdw,
    u16* __restrict__ vout, float* __restrict__ ssq, float* __restrict__ S)
{
    const int b = blockIdx.y;
    const int tile = blockIdx.x;          // 0..511
    const int y = tile >> 1;              // 0..255
    const int tx = (tile & 1) * 128;
    const int tid = threadIdx.x;
    const int px = tid & 127;
    const int half = tid >> 7;            // wave-uniform
    const int xg = tx + px;

    __shared__ __align__(16) u16 qs[96][136];
    __shared__ __align__(16) u16 ks[96][136];

    #pragma unroll 2
    for (int ci = 0; ci < 48; ++ci) {
        const int c = half * 48 + ci;
        const float* wq = wqdw + c * 9;
        const float* wk = wkvdw + c * 9;
        const float* wv = wkvdw + (96 + c) * 9;
        const u16* qrow = qpre + ((size_t)(b * 96 + c)) * HWn;
        const u16* krow = kvpre + ((size_t)(b * 192 + c)) * HWn;
        const u16* vrow = kvpre + ((size_t)(b * 192 + 96 + c)) * HWn;
        float qv = 0.f, kv = 0.f, vv = 0.f;
        #pragma unroll
        for (int dy = -1; dy <= 1; ++dy) {
            const int yy = y + dy;
            if ((unsigned)yy >= 256u) continue;
            const int rb = yy * 256;
            #pragma unroll
            for (int dx = -1; dx <= 1; ++dx) {
                const int xx = xg + dx;
                if ((unsigned)xx >= 256u) continue;
                const int widx = (dy + 1) * 3 + (dx + 1);
                const int a = rb + xx;
                qv = fmaf(wq[widx], bf2f(qrow[a]), qv);
                kv = fmaf(wk[widx], bf2f(krow[a]), kv);
                vv = fmaf(wv[widx], bf2f(vrow[a]), vv);
            }
        }
        qs[c][px] = f2bf(qv);
        ks[c][px] = f2bf(kv);
        vout[((size_t)(b * 96 + c)) * HWn + y * 256 + xg] = f2bf(vv);
    }
    __syncthreads();

    // sum of squares per channel row (q and k)
    if (tid < 192) {
        const int which = tid / 96;       // 0=q, 1=k
        const int c = tid % 96;
        const uint4* r = reinterpret_cast<const uint4*>(which == 0 ? &qs[c][0] : &ks[c][0]);
        float s = 0.f;
        #pragma unroll
        for (int pch = 0; pch < 16; ++pch) {
            const uint4 a = r[pch];
            s += sq2bf(a.x) + sq2bf(a.y) + sq2bf(a.z) + sq2bf(a.w);
        }
        atomicAdd(ssq + b * 192 + which * 96 + c, s);
    }

    // S[h][i][j] += sum_px q[h*24+i][px] * k[h*24+j][px]; 2304 pairs, 9 per thread
    #pragma unroll 1
    for (int kk = 0; kk < 9; ++kk) {
        const int id = tid * 9 + kk;      // 0..2303
        const int h = id / 576;
        const int r = id % 576;
        const int i = r / 24, j = r % 24;
        const int cq = h * 24 + i, ck = h * 24 + j;
        const uint4* qr = reinterpret_cast<const uint4*>(&qs[cq][0]);
        const uint4* kr = reinterpret_cast<const uint4*>(&ks[ck][0]);
        float s = 0.f;
        #pragma unroll
        for (int pch = 0; pch < 16; ++pch) {
            const uint4 a = qr[pch];
            const uint4 bb = kr[pch];
            s += dot2bf(a.x, bb.x) + dot2bf(a.y, bb.y) + dot2bf(a.z, bb.z) + dot2bf(a.w, bb.w);
        }
        atomicAdd(S + b * 2304 + id, s);
    }
}

// K3: normalize, softmax, fold w_out with block-diag attn -> Mt[b][dg][oc]
__global__ __launch_bounds__(256) void k_attn_fold(
    const float* __restrict__ ssq, const float* __restrict__ S,
    const float* __restrict__ temp, const float* __restrict__ w_out,
    float* __restrict__ Mt)
{
    const int b = blockIdx.x;
    const int tid = threadIdx.x;
    __shared__ float rq[96], rk[96], att[2304];

    if (tid < 96) {
        rq[tid] = 1.f / fmaxf(sqrtf(ssq[b * 192 + tid]), 1e-12f);
    } else if (tid < 192) {
        const int c = tid - 96;
        rk[c] = 1.f / fmaxf(sqrtf(ssq[b * 192 + 96 + c]), 1e-12f);
    }
    __syncthreads();

    if (tid < 96) {
        const int h = tid / 24, i = tid % 24;
        const float tmp = temp[h];
        const float rqi = rq[h * 24 + i];
        float l[24];
        float m = -1e30f;
        #pragma unroll
        for (int j = 0; j < 24; ++j) {
            l[j] = S[b * 2304 + (h * 24 + i) * 24 + j] * rqi * rk[h * 24 + j] * tmp;
            m = fmaxf(m, l[j]);
        }
        float ssum = 0.f;
        #pragma unroll
        for (int j = 0; j < 24; ++j) { l[j] = expf(l[j] - m); ssum += l[j]; }
        const float inv = 1.f / ssum;
        #pragma unroll
        for (int j = 0; j < 24; ++j) att[(h * 24 + i) * 24 + j] = l[j] * inv;
    }
    __syncthreads();

    // Mt[dg][oc] = sum_{i<24} w_out[oc][h*24+i] * att[h][i][dg%24], h = dg/24
    for (int k = 0; k < 36; ++k) {
        const int id = k * 256 + tid;     // 0..9215
        const int dg = id / 96, oc = id % 96;
        const int h = dg / 24, d24 = dg % 24;
        float s = 0.f;
        #pragma unroll
        for (int i = 0; i < 24; ++i) {
            s += w_out[oc * 96 + h * 24 + i] * att[(h * 24 + i) * 24 + d24];
        }
        Mt[b * 9216 + id] = s;
    }
}

// K4: out = M @ v per batch. grid (64 px-tiles, 3 oc-tiles, 4 b).
__global__ __launch_bounds__(256) void k_out_gemm(
    const u16* __restrict__ v, const float* __restrict__ Mt,
    float* __restrict__ out)
{
    const int b = blockIdx.z;
    const int oc0 = blockIdx.y * 32;
    const int tid = threadIdx.x;
    const int p = blockIdx.x * 1024 + tid * 4;

    __shared__ float wm[96 * 32];         // wm[dg][j] = M[oc0+j][dg]
    for (int idx = tid; idx < 96 * 32; idx += 256) {
        const int dg = idx / 32, j = idx % 32;
        wm[idx] = Mt[b * 9216 + dg * 96 + oc0 + j];
    }
    __syncthreads();

    float acc[32][4];
    #pragma unroll
    for (int oc = 0; oc < 32; ++oc) { acc[oc][0] = acc[oc][1] = acc[oc][2] = acc[oc][3] = 0.f; }

    const u16* vb = v + (size_t)b * 96 * HWn + p;
    for (int dg = 0; dg < 96; ++dg) {
        const ushort4 u = *reinterpret_cast<const ushort4*>(vb + (size_t)dg * HWn);
        const float v0 = bf2f(u.x), v1 = bf2f(u.y), v2 = bf2f(u.z), v3 = bf2f(u.w);
        const float* wr = &wm[dg * 32];
        #pragma unroll
        for (int oc = 0; oc < 32; ++oc) {
            const float wv = wr[oc];
            acc[oc][0] = fmaf(wv, v0, acc[oc][0]);
            acc[oc][1] = fmaf(wv, v1, acc[oc][1]);
            acc[oc][2] = fmaf(wv, v2, acc[oc][2]);
            acc[oc][3] = fmaf(wv, v3, acc[oc][3]);
        }
    }
    #pragma unroll
    for (int oc = 0; oc < 32; ++oc) {
        const float4 o4 = make_float4(acc[oc][0], acc[oc][1], acc[oc][2], acc[oc][3]);
        *reinterpret_cast<float4*>(out + ((size_t)(b * 96 + oc0 + oc)) * HWn + p) = o4;
    }
}

extern "C" void kernel_launch(void* const* d_in, const int* in_sizes, int n_in,
                              void* d_out, int out_size, void* d_ws, size_t ws_size,
                              hipStream_t stream) {
    (void)in_sizes; (void)n_in; (void)out_size; (void)ws_size;
    const float* x      = (const float*)d_in[0];
    const float* ff     = (const float*)d_in[1];
    const float* w_q    = (const float*)d_in[2];
    const float* w_kv   = (const float*)d_in[3];
    const float* w_q_dw = (const float*)d_in[4];
    const float* w_kv_dw= (const float*)d_in[5];
    const float* w_out  = (const float*)d_in[6];
    const float* temp   = (const float*)d_in[7];
    float* out = (float*)d_out;

    char* ws = (char*)d_ws;
    u16* qpre   = (u16*)(ws);                      //  50,331,648 B
    u16* kvpre  = (u16*)(ws + 50331648);           // 100,663,296 B
    u16* vbuf   = (u16*)(ws + 150994944);          //  50,331,648 B
    float* ssq  = (float*)(ws + 201326592);        //       3,072 B
    float* S    = (float*)(ws + 201329664);        //      36,864 B
    float* Mt   = (float*)(ws + 201366528);        //     147,456 B

    hipMemsetAsync(ssq, 0, 3072 + 36864, stream);

    k_conv1x1_in<<<dim3(64, 9, 4), 256, 0, stream>>>(ff, x, w_q, w_kv, qpre, kvpre);
    k_dw_reduce<<<dim3(512, 4), 256, 0, stream>>>(qpre, kvpre, w_q_dw, w_kv_dw, vbuf, ssq, S);
    k_attn_fold<<<4, 256, 0, stream>>>(ssq, S, temp, w_out, Mt);
    k_out_gemm<<<dim3(64, 3, 4), 256, 0, stream>>>(vbuf, Mt, out);
}

// Round 2
// 540.866 us; speedup vs baseline: 1.8027x; 1.8027x over previous
//
#include <hip/hip_runtime.h>
#include <hip/hip_bf16.h>

typedef unsigned int u32;
typedef unsigned short u16;

static constexpr int Cn = 96;
static constexpr int HWn = 65536;

__device__ __forceinline__ float bf2f(u16 u) {
    union { u32 i; float f; } z; z.i = ((u32)u) << 16; return z.f;
}
__device__ __forceinline__ u16 f2bf(float f) {
    __hip_bfloat16 h = __float2bfloat16(f);
    return *reinterpret_cast<u16*>(&h);
}
__device__ __forceinline__ u32 pack2(float a, float b) {
    return ((u32)f2bf(b) << 16) | (u32)f2bf(a);
}
__device__ __forceinline__ float lo2f(u32 u) {
    union { u32 i; float f; } z; z.i = u << 16; return z.f;
}
__device__ __forceinline__ float hi2f(u32 u) {
    union { u32 i; float f; } z; z.i = u & 0xffff0000u; return z.f;
}
__device__ __forceinline__ float dot2bf(u32 a, u32 b) {
    union { u32 i; float f; } al, ah, bl, bh;
    al.i = a << 16; ah.i = a & 0xffff0000u;
    bl.i = b << 16; bh.i = b & 0xffff0000u;
    return fmaf(al.f, bl.f, ah.f * bh.f);
}
__device__ __forceinline__ float sq2bf(u32 a) {
    union { u32 i; float f; } al, ah;
    al.i = a << 16; ah.i = a & 0xffff0000u;
    return fmaf(al.f, al.f, ah.f * ah.f);
}

// K1: pointwise convs. grid (64 px-tiles, 9 oc-tiles, 4 b). 32 oc x 1024 px per block.
__global__ __launch_bounds__(256) void k_conv1x1_in(
    const float* __restrict__ ff, const float* __restrict__ x,
    const float* __restrict__ w_q, const float* __restrict__ w_kv,
    u16* __restrict__ qpre, u16* __restrict__ kvpre)
{
    const int b = blockIdx.z;
    const int t = blockIdx.y;            // 0..2: q from ff; 3..8: kv from x
    const int tid = threadIdx.x;
    const int p = blockIdx.x * 1024 + tid * 4;

    const float* src; const float* w; u16* dst;
    if (t < 3) {
        src = ff + (size_t)b * Cn * HWn;
        w = w_q + t * 32 * Cn;
        dst = qpre + (size_t)b * Cn * HWn + (size_t)(t * 32) * HWn;
    } else {
        src = x + (size_t)b * Cn * HWn;
        w = w_kv + (t - 3) * 32 * Cn;
        dst = kvpre + (size_t)b * 2 * Cn * HWn + (size_t)((t - 3) * 32) * HWn;
    }

    __shared__ float wt[96 * 32];   // transposed: wt[i][oc]
    for (int idx = tid; idx < 96 * 32; idx += 256) {
        const int oc = idx / 96, i = idx % 96;
        wt[i * 32 + oc] = w[idx];
    }
    __syncthreads();

    float acc[32][4];
    #pragma unroll
    for (int oc = 0; oc < 32; ++oc) { acc[oc][0] = acc[oc][1] = acc[oc][2] = acc[oc][3] = 0.f; }

    for (int i = 0; i < 96; ++i) {
        const float4 v = *reinterpret_cast<const float4*>(src + (size_t)i * HWn + p);
        const float* wr = &wt[i * 32];
        #pragma unroll
        for (int oc = 0; oc < 32; ++oc) {
            const float wv = wr[oc];
            acc[oc][0] = fmaf(wv, v.x, acc[oc][0]);
            acc[oc][1] = fmaf(wv, v.y, acc[oc][1]);
            acc[oc][2] = fmaf(wv, v.z, acc[oc][2]);
            acc[oc][3] = fmaf(wv, v.w, acc[oc][3]);
        }
    }
    #pragma unroll
    for (int oc = 0; oc < 32; ++oc) {
        ushort4 s;
        s.x = f2bf(acc[oc][0]); s.y = f2bf(acc[oc][1]);
        s.z = f2bf(acc[oc][2]); s.w = f2bf(acc[oc][3]);
        *reinterpret_cast<ushort4*>(dst + (size_t)oc * HWn + p) = s;
    }
}

// K2: fused depthwise 3x3 + reductions. One block per (row y, batch b).
// 512 threads. Conv: 18 iters x (16 planes x 32 chunks of 8 px), vectorized loads.
// q,k conv rows staged in LDS; ssq + S reduced from LDS; v written to global.
__global__ __launch_bounds__(512) void k_dw_fused(
    const u16* __restrict__ qpre, const u16* __restrict__ kvpre,
    const float* __restrict__ wqdw, const float* __restrict__ wkvdw,
    u16* __restrict__ vout, float* __restrict__ ssq, float* __restrict__ Sg)
{
    // XCD swizzle: consecutive blockIdx round-robin XCDs; remap so each XCD
    // gets a contiguous span of rows (vertical-halo reuse hits that XCD's L2).
    const int bid = blockIdx.x;                 // 0..1023
    const int wg = (bid & 7) * 128 + (bid >> 3);
    const int y = wg & 255;
    const int b = wg >> 8;
    const int tid = threadIdx.x;

    __shared__ __align__(16) u16 qs[96][264];   // pitch 264 u16 = 528 B (bank step 4)
    __shared__ __align__(16) u16 ks[96][264];

    const int chunk = tid & 31;
    const int x0 = chunk * 8;

    #pragma unroll 1
    for (int it = 0; it < 18; ++it) {
        const int p = it * 16 + (tid >> 5);     // plane 0..287, wave-uniform type
        const u16* src; const float* wp; int c;
        if (p < 96)       { c = p;       src = qpre  + ((size_t)(b * 96 + c)) * HWn;       wp = wqdw  + c * 9; }
        else if (p < 192) { c = p - 96;  src = kvpre + ((size_t)(b * 192 + c)) * HWn;      wp = wkvdw + c * 9; }
        else              { c = p - 192; src = kvpre + ((size_t)(b * 192 + 96 + c)) * HWn; wp = wkvdw + (96 + c) * 9; }

        float a0 = 0.f, a1 = 0.f, a2 = 0.f, a3 = 0.f, a4 = 0.f, a5 = 0.f, a6 = 0.f, a7 = 0.f;

        #pragma unroll
        for (int r = 0; r < 3; ++r) {
            const int ry = y + r - 1;
            const float w0 = wp[r * 3 + 0], w1 = wp[r * 3 + 1], w2 = wp[r * 3 + 2];
            float v0, v1, v2, v3, v4, v5, v6, v7, v8, v9;
            if ((unsigned)ry < 256u) {
                const u16* row = src + ry * 256 + x0;
                const uint4 m = *reinterpret_cast<const uint4*>(row);
                v0 = (x0 > 0)   ? bf2f(row[-1]) : 0.f;
                v9 = (x0 < 248) ? bf2f(row[8])  : 0.f;
                v1 = lo2f(m.x); v2 = hi2f(m.x);
                v3 = lo2f(m.y); v4 = hi2f(m.y);
                v5 = lo2f(m.z); v6 = hi2f(m.z);
                v7 = lo2f(m.w); v8 = hi2f(m.w);
            } else {
                v0 = v1 = v2 = v3 = v4 = v5 = v6 = v7 = v8 = v9 = 0.f;
            }
            a0 = fmaf(w0, v0, fmaf(w1, v1, fmaf(w2, v2, a0)));
            a1 = fmaf(w0, v1, fmaf(w1, v2, fmaf(w2, v3, a1)));
            a2 = fmaf(w0, v2, fmaf(w1, v3, fmaf(w2, v4, a2)));
            a3 = fmaf(w0, v3, fmaf(w1, v4, fmaf(w2, v5, a3)));
            a4 = fmaf(w0, v4, fmaf(w1, v5, fmaf(w2, v6, a4)));
            a5 = fmaf(w0, v5, fmaf(w1, v6, fmaf(w2, v7, a5)));
            a6 = fmaf(w0, v6, fmaf(w1, v7, fmaf(w2, v8, a6)));
            a7 = fmaf(w0, v7, fmaf(w1, v8, fmaf(w2, v9, a7)));
        }

        const uint4 o = make_uint4(pack2(a0, a1), pack2(a2, a3), pack2(a4, a5), pack2(a6, a7));
        if (p < 96) {
            *reinterpret_cast<uint4*>(&qs[c][x0]) = o;
        } else if (p < 192) {
            *reinterpret_cast<uint4*>(&ks[c][x0]) = o;
        } else {
            *reinterpret_cast<uint4*>(vout + ((size_t)(b * 96 + c)) * HWn + y * 256 + x0) = o;
        }
    }
    __syncthreads();

    // ssq: 192 rows x 2 halves = 384 tasks
    if (tid < 384) {
        const int half = tid >= 192;
        const int r = tid - half * 192;         // 0..191: 0..95 q, 96..191 k
        const uint4* rr = reinterpret_cast<const uint4*>(
            r < 96 ? &qs[r][half * 128] : &ks[r - 96][half * 128]);
        float s = 0.f;
        #pragma unroll
        for (int pch = 0; pch < 16; ++pch) {
            const uint4 a = rr[pch];
            s += sq2bf(a.x) + sq2bf(a.y) + sq2bf(a.z) + sq2bf(a.w);
        }
        atomicAdd(ssq + b * 192 + r, s);
    }

    // S: 2304 pairs x 2 halves = 4608 tasks, 9 per thread (half-major mapping)
    #pragma unroll 1
    for (int kk = 0; kk < 9; ++kk) {
        const int task = kk * 512 + tid;        // 0..4607
        const int half = task >= 2304;
        const int pair = task - half * 2304;
        const int h = pair / 576;
        const int rem = pair - h * 576;
        const int i = rem / 24, j = rem - (rem / 24) * 24;
        const uint4* qr = reinterpret_cast<const uint4*>(&qs[h * 24 + i][half * 128]);
        const uint4* kr = reinterpret_cast<const uint4*>(&ks[h * 24 + j][half * 128]);
        float s = 0.f;
        #pragma unroll
        for (int pch = 0; pch < 16; ++pch) {
            const uint4 a = qr[pch];
            const uint4 bb = kr[pch];
            s += dot2bf(a.x, bb.x) + dot2bf(a.y, bb.y) + dot2bf(a.z, bb.z) + dot2bf(a.w, bb.w);
        }
        atomicAdd(Sg + b * 2304 + pair, s);
    }
}

// K3: normalize, softmax, fold w_out with block-diag attn -> Mt[b][dg][oc]
__global__ __launch_bounds__(256) void k_attn_fold(
    const float* __restrict__ ssq, const float* __restrict__ S,
    const float* __restrict__ temp, const float* __restrict__ w_out,
    float* __restrict__ Mt)
{
    const int b = blockIdx.x;
    const int tid = threadIdx.x;
    __shared__ float rq[96], rk[96], att[2304];

    if (tid < 96) {
        rq[tid] = 1.f / fmaxf(sqrtf(ssq[b * 192 + tid]), 1e-12f);
    } else if (tid < 192) {
        const int c = tid - 96;
        rk[c] = 1.f / fmaxf(sqrtf(ssq[b * 192 + 96 + c]), 1e-12f);
    }
    __syncthreads();

    if (tid < 96) {
        const int h = tid / 24, i = tid % 24;
        const float tmp = temp[h];
        const float rqi = rq[h * 24 + i];
        float l[24];
        float m = -1e30f;
        #pragma unroll
        for (int j = 0; j < 24; ++j) {
            l[j] = S[b * 2304 + (h * 24 + i) * 24 + j] * rqi * rk[h * 24 + j] * tmp;
            m = fmaxf(m, l[j]);
        }
        float ssum = 0.f;
        #pragma unroll
        for (int j = 0; j < 24; ++j) { l[j] = expf(l[j] - m); ssum += l[j]; }
        const float inv = 1.f / ssum;
        #pragma unroll
        for (int j = 0; j < 24; ++j) att[(h * 24 + i) * 24 + j] = l[j] * inv;
    }
    __syncthreads();

    // Mt[dg][oc] = sum_{i<24} w_out[oc][h*24+i] * att[h][i][dg%24], h = dg/24
    for (int k = 0; k < 36; ++k) {
        const int id = k * 256 + tid;     // 0..9215
        const int dg = id / 96, oc = id % 96;
        const int h = dg / 24, d24 = dg % 24;
        float s = 0.f;
        #pragma unroll
        for (int i = 0; i < 24; ++i) {
            s += w_out[oc * 96 + h * 24 + i] * att[(h * 24 + i) * 24 + d24];
        }
        Mt[b * 9216 + id] = s;
    }
}

// K4: out = M @ v per batch. grid (64 px-tiles, 3 oc-tiles, 4 b).
__global__ __launch_bounds__(256) void k_out_gemm(
    const u16* __restrict__ v, const float* __restrict__ Mt,
    float* __restrict__ out)
{
    const int b = blockIdx.z;
    const int oc0 = blockIdx.y * 32;
    const int tid = threadIdx.x;
    const int p = blockIdx.x * 1024 + tid * 4;

    __shared__ float wm[96 * 32];         // wm[dg][j] = M[oc0+j][dg]
    for (int idx = tid; idx < 96 * 32; idx += 256) {
        const int dg = idx / 32, j = idx % 32;
        wm[idx] = Mt[b * 9216 + dg * 96 + oc0 + j];
    }
    __syncthreads();

    float acc[32][4];
    #pragma unroll
    for (int oc = 0; oc < 32; ++oc) { acc[oc][0] = acc[oc][1] = acc[oc][2] = acc[oc][3] = 0.f; }

    const u16* vb = v + (size_t)b * 96 * HWn + p;
    for (int dg = 0; dg < 96; ++dg) {
        const ushort4 u = *reinterpret_cast<const ushort4*>(vb + (size_t)dg * HWn);
        const float v0 = bf2f(u.x), v1 = bf2f(u.y), v2 = bf2f(u.z), v3 = bf2f(u.w);
        const float* wr = &wm[dg * 32];
        #pragma unroll
        for (int oc = 0; oc < 32; ++oc) {
            const float wv = wr[oc];
            acc[oc][0] = fmaf(wv, v0, acc[oc][0]);
            acc[oc][1] = fmaf(wv, v1, acc[oc][1]);
            acc[oc][2] = fmaf(wv, v2, acc[oc][2]);
            acc[oc][3] = fmaf(wv, v3, acc[oc][3]);
        }
    }
    #pragma unroll
    for (int oc = 0; oc < 32; ++oc) {
        const float4 o4 = make_float4(acc[oc][0], acc[oc][1], acc[oc][2], acc[oc][3]);
        *reinterpret_cast<float4*>(out + ((size_t)(b * 96 + oc0 + oc)) * HWn + p) = o4;
    }
}

extern "C" void kernel_launch(void* const* d_in, const int* in_sizes, int n_in,
                              void* d_out, int out_size, void* d_ws, size_t ws_size,
                              hipStream_t stream) {
    (void)in_sizes; (void)n_in; (void)out_size; (void)ws_size;
    const float* x      = (const float*)d_in[0];
    const float* ff     = (const float*)d_in[1];
    const float* w_q    = (const float*)d_in[2];
    const float* w_kv   = (const float*)d_in[3];
    const float* w_q_dw = (const float*)d_in[4];
    const float* w_kv_dw= (const float*)d_in[5];
    const float* w_out  = (const float*)d_in[6];
    const float* temp   = (const float*)d_in[7];
    float* out = (float*)d_out;

    char* ws = (char*)d_ws;
    u16* qpre   = (u16*)(ws);                      //  50,331,648 B
    u16* kvpre  = (u16*)(ws + 50331648);           // 100,663,296 B
    u16* vbuf   = (u16*)(ws + 150994944);          //  50,331,648 B
    float* ssq  = (float*)(ws + 201326592);        //       3,072 B
    float* S    = (float*)(ws + 201329664);        //      36,864 B
    float* Mt   = (float*)(ws + 201366528);        //     147,456 B

    hipMemsetAsync(ssq, 0, 3072 + 36864, stream);

    k_conv1x1_in<<<dim3(64, 9, 4), 256, 0, stream>>>(ff, x, w_q, w_kv, qpre, kvpre);
    k_dw_fused<<<dim3(1024), 512, 0, stream>>>(qpre, kvpre, w_q_dw, w_kv_dw, vbuf, ssq, S);
    k_attn_fold<<<4, 256, 0, stream>>>(ssq, S, temp, w_out, Mt);
    k_out_gemm<<<dim3(64, 3, 4), 256, 0, stream>>>(vbuf, Mt, out);
}

// Round 3
// 445.311 us; speedup vs baseline: 2.1895x; 1.2146x over previous
//
#include <hip/hip_runtime.h>
#include <hip/hip_bf16.h>

typedef unsigned int u32;
typedef unsigned short u16;

static constexpr int Cn = 96;
static constexpr int HWn = 65536;

typedef __attribute__((ext_vector_type(8))) short bf16x8;
typedef __attribute__((ext_vector_type(4))) float f32x4;

__device__ __forceinline__ float bf2f(u16 u) {
    union { u32 i; float f; } z; z.i = ((u32)u) << 16; return z.f;
}
__device__ __forceinline__ u16 f2bf(float f) {
    __hip_bfloat16 h = __float2bfloat16(f);
    return *reinterpret_cast<u16*>(&h);
}
__device__ __forceinline__ u32 pack2(float a, float b) {
    return ((u32)f2bf(b) << 16) | (u32)f2bf(a);
}
__device__ __forceinline__ float lo2f(u32 u) {
    union { u32 i; float f; } z; z.i = u << 16; return z.f;
}
__device__ __forceinline__ float hi2f(u32 u) {
    union { u32 i; float f; } z; z.i = u & 0xffff0000u; return z.f;
}
__device__ __forceinline__ float dot2bf(u32 a, u32 b) {
    union { u32 i; float f; } al, ah, bl, bh;
    al.i = a << 16; ah.i = a & 0xffff0000u;
    bl.i = b << 16; bh.i = b & 0xffff0000u;
    return fmaf(al.f, bl.f, ah.f * bh.f);
}
__device__ __forceinline__ float sq2bf(u32 a) {
    union { u32 i; float f; } al, ah;
    al.i = a << 16; ah.i = a & 0xffff0000u;
    return fmaf(al.f, al.f, ah.f * ah.f);
}

// Swizzled LDS offset (u16 units) for transposed X tile: [px 0..127][ic 0..95],
// granule = 8 ic; swz spreads banks for both b16 transpose-writes and b128 reads.
__device__ __forceinline__ int xoff(int px, int icb) {
    return px * 128 + (((icb ^ (px & 7) ^ ((px >> 3) & 7))) << 3);
}

// Tiny: split conv1x1 weights into bf16 hi/lo, layout [sec*96+oc][ic]
__global__ __launch_bounds__(256) void k_prep_w(
    const float* __restrict__ wq, const float* __restrict__ wkv,
    u16* __restrict__ whi, u16* __restrict__ wlo)
{
    const int i = blockIdx.x * 256 + threadIdx.x;   // 0..27647
    if (i >= 288 * 96) return;
    const int row = i / 96, ic = i % 96;
    const float w = (row < 96) ? wq[row * 96 + ic] : wkv[(row - 96) * 96 + ic];
    const u16 h = f2bf(w);
    whi[i] = h;
    wlo[i] = f2bf(w - bf2f(h));
}

// K1: conv1x1 via MFMA. grid (512 px-tiles, 3 sec, 4 b), 256 thr (4 waves 2x2).
// Out tile [96 oc][128 px]; K=96; passes Whi*Xhi + Whi*Xlo + Wlo*Xhi.
__global__ __launch_bounds__(256) void k_conv_mfma(
    const float* __restrict__ ff, const float* __restrict__ x,
    const u16* __restrict__ whi, const u16* __restrict__ wlo,
    u16* __restrict__ qpre, u16* __restrict__ kvpre)
{
    const int b = blockIdx.z, sec = blockIdx.y;
    const int px0 = blockIdx.x * 128;
    const int tid = threadIdx.x;

    __shared__ __align__(16) u16 xhi[16384];
    __shared__ __align__(16) u16 xlo[16384];

    const float* src = (sec == 0 ? ff : x) + (size_t)b * 96 * HWn;
    const u16* wh = whi + sec * 96 * 96;
    const u16* wl = wlo + sec * 96 * 96;
    u16* dst = (sec == 0) ? (qpre + (size_t)b * 96 * HWn)
                          : (kvpre + (size_t)b * 192 * HWn + (size_t)(sec - 1) * 96 * HWn);

    // stage: thread -> (ic = p*16 + tid>>4, px run of 8 at (tid&15)*8)
    const int icq = tid >> 4;
    const int pxs = (tid & 15) * 8;
    #pragma unroll 1
    for (int p = 0; p < 6; ++p) {
        const int ic = p * 16 + icq;
        const float* rp = src + (size_t)ic * HWn + px0 + pxs;
        const float4 va = *reinterpret_cast<const float4*>(rp);
        const float4 vb = *reinterpret_cast<const float4*>(rp + 4);
        const int icb = ic >> 3, icl = ic & 7;
        float e[8] = {va.x, va.y, va.z, va.w, vb.x, vb.y, vb.z, vb.w};
        #pragma unroll
        for (int j = 0; j < 8; ++j) {
            const int o = xoff(pxs + j, icb) + icl;
            const u16 h = f2bf(e[j]);
            xhi[o] = h;
            xlo[o] = f2bf(e[j] - bf2f(h));
        }
    }
    __syncthreads();

    const int lane = tid & 63;
    const int wv = tid >> 6;
    const int oc0 = (wv >> 1) * 48;
    const int pxw = (wv & 1) * 64;
    const int lr = lane & 15, lg = lane >> 4;

    f32x4 acc[3][4];
    #pragma unroll
    for (int m = 0; m < 3; ++m)
        #pragma unroll
        for (int n = 0; n < 4; ++n)
            acc[m][n] = (f32x4){0.f, 0.f, 0.f, 0.f};

    #pragma unroll 1
    for (int s = 0; s < 9; ++s) {
        const int pass = s / 3, kt = s - pass * 3;
        const int kb = kt * 32;
        const u16* wsrc = (pass == 2) ? wl : wh;
        const u16* xsrc = (pass == 1) ? xlo : xhi;
        bf16x8 A[3], B[4];
        #pragma unroll
        for (int m = 0; m < 3; ++m) {
            const int row = oc0 + m * 16 + lr;
            A[m] = *(const bf16x8*)(wsrc + row * 96 + kb + lg * 8);
        }
        #pragma unroll
        for (int n = 0; n < 4; ++n) {
            const int px = pxw + n * 16 + lr;
            B[n] = *(const bf16x8*)(xsrc + xoff(px, (kb >> 3) + lg));
        }
        #pragma unroll
        for (int m = 0; m < 3; ++m)
            #pragma unroll
            for (int n = 0; n < 4; ++n)
                acc[m][n] = __builtin_amdgcn_mfma_f32_16x16x32_bf16(A[m], B[n], acc[m][n], 0, 0, 0);
    }

    #pragma unroll
    for (int m = 0; m < 3; ++m) {
        #pragma unroll
        for (int i = 0; i < 4; ++i) {
            const int oc = oc0 + m * 16 + lg * 4 + i;
            u16* drow = dst + (size_t)oc * HWn + px0;
            #pragma unroll
            for (int n = 0; n < 4; ++n)
                drow[pxw + n * 16 + lr] = f2bf(acc[m][n][i]);
        }
    }
}

// K2: fused depthwise 3x3 + reductions (unchanged from R2).
__global__ __launch_bounds__(512) void k_dw_fused(
    const u16* __restrict__ qpre, const u16* __restrict__ kvpre,
    const float* __restrict__ wqdw, const float* __restrict__ wkvdw,
    u16* __restrict__ vout, float* __restrict__ ssq, float* __restrict__ Sg)
{
    const int bid = blockIdx.x;
    const int wg = (bid & 7) * 128 + (bid >> 3);
    const int y = wg & 255;
    const int b = wg >> 8;
    const int tid = threadIdx.x;

    __shared__ __align__(16) u16 qs[96][264];
    __shared__ __align__(16) u16 ks[96][264];

    const int chunk = tid & 31;
    const int x0 = chunk * 8;

    #pragma unroll 1
    for (int it = 0; it < 18; ++it) {
        const int p = it * 16 + (tid >> 5);
        const u16* src; const float* wp; int c;
        if (p < 96)       { c = p;       src = qpre  + ((size_t)(b * 96 + c)) * HWn;       wp = wqdw  + c * 9; }
        else if (p < 192) { c = p - 96;  src = kvpre + ((size_t)(b * 192 + c)) * HWn;      wp = wkvdw + c * 9; }
        else              { c = p - 192; src = kvpre + ((size_t)(b * 192 + 96 + c)) * HWn; wp = wkvdw + (96 + c) * 9; }

        float a0 = 0.f, a1 = 0.f, a2 = 0.f, a3 = 0.f, a4 = 0.f, a5 = 0.f, a6 = 0.f, a7 = 0.f;

        #pragma unroll
        for (int r = 0; r < 3; ++r) {
            const int ry = y + r - 1;
            const float w0 = wp[r * 3 + 0], w1 = wp[r * 3 + 1], w2 = wp[r * 3 + 2];
            float v0, v1, v2, v3, v4, v5, v6, v7, v8, v9;
            if ((unsigned)ry < 256u) {
                const u16* row = src + ry * 256 + x0;
                const uint4 m = *reinterpret_cast<const uint4*>(row);
                v0 = (x0 > 0)   ? bf2f(row[-1]) : 0.f;
                v9 = (x0 < 248) ? bf2f(row[8])  : 0.f;
                v1 = lo2f(m.x); v2 = hi2f(m.x);
                v3 = lo2f(m.y); v4 = hi2f(m.y);
                v5 = lo2f(m.z); v6 = hi2f(m.z);
                v7 = lo2f(m.w); v8 = hi2f(m.w);
            } else {
                v0 = v1 = v2 = v3 = v4 = v5 = v6 = v7 = v8 = v9 = 0.f;
            }
            a0 = fmaf(w0, v0, fmaf(w1, v1, fmaf(w2, v2, a0)));
            a1 = fmaf(w0, v1, fmaf(w1, v2, fmaf(w2, v3, a1)));
            a2 = fmaf(w0, v2, fmaf(w1, v3, fmaf(w2, v4, a2)));
            a3 = fmaf(w0, v3, fmaf(w1, v4, fmaf(w2, v5, a3)));
            a4 = fmaf(w0, v4, fmaf(w1, v5, fmaf(w2, v6, a4)));
            a5 = fmaf(w0, v5, fmaf(w1, v6, fmaf(w2, v7, a5)));
            a6 = fmaf(w0, v6, fmaf(w1, v7, fmaf(w2, v8, a6)));
            a7 = fmaf(w0, v7, fmaf(w1, v8, fmaf(w2, v9, a7)));
        }

        const uint4 o = make_uint4(pack2(a0, a1), pack2(a2, a3), pack2(a4, a5), pack2(a6, a7));
        if (p < 96) {
            *reinterpret_cast<uint4*>(&qs[c][x0]) = o;
        } else if (p < 192) {
            *reinterpret_cast<uint4*>(&ks[c][x0]) = o;
        } else {
            *reinterpret_cast<uint4*>(vout + ((size_t)(b * 96 + c)) * HWn + y * 256 + x0) = o;
        }
    }
    __syncthreads();

    if (tid < 384) {
        const int half = tid >= 192;
        const int r = tid - half * 192;
        const uint4* rr = reinterpret_cast<const uint4*>(
            r < 96 ? &qs[r][half * 128] : &ks[r - 96][half * 128]);
        float s = 0.f;
        #pragma unroll
        for (int pch = 0; pch < 16; ++pch) {
            const uint4 a = rr[pch];
            s += sq2bf(a.x) + sq2bf(a.y) + sq2bf(a.z) + sq2bf(a.w);
        }
        atomicAdd(ssq + b * 192 + r, s);
    }

    #pragma unroll 1
    for (int kk = 0; kk < 9; ++kk) {
        const int task = kk * 512 + tid;
        const int half = task >= 2304;
        const int pair = task - half * 2304;
        const int h = pair / 576;
        const int rem = pair - h * 576;
        const int i = rem / 24, j = rem - (rem / 24) * 24;
        const uint4* qr = reinterpret_cast<const uint4*>(&qs[h * 24 + i][half * 128]);
        const uint4* kr = reinterpret_cast<const uint4*>(&ks[h * 24 + j][half * 128]);
        float s = 0.f;
        #pragma unroll
        for (int pch = 0; pch < 16; ++pch) {
            const uint4 a = qr[pch];
            const uint4 bb = kr[pch];
            s += dot2bf(a.x, bb.x) + dot2bf(a.y, bb.y) + dot2bf(a.z, bb.z) + dot2bf(a.w, bb.w);
        }
        atomicAdd(Sg + b * 2304 + pair, s);
    }
}

// K3: normalize, softmax, fold w_out with block-diag attn -> Mhi/Mlo [oc][dg] bf16
__global__ __launch_bounds__(256) void k_attn_fold(
    const float* __restrict__ ssq, const float* __restrict__ S,
    const float* __restrict__ temp, const float* __restrict__ w_out,
    u16* __restrict__ mhi, u16* __restrict__ mlo)
{
    const int b = blockIdx.x;
    const int tid = threadIdx.x;
    __shared__ float rq[96], rk[96], att[2304];

    if (tid < 96) {
        rq[tid] = 1.f / fmaxf(sqrtf(ssq[b * 192 + tid]), 1e-12f);
    } else if (tid < 192) {
        const int c = tid - 96;
        rk[c] = 1.f / fmaxf(sqrtf(ssq[b * 192 + 96 + c]), 1e-12f);
    }
    __syncthreads();

    if (tid < 96) {
        const int h = tid / 24, i = tid % 24;
        const float tmp = temp[h];
        const float rqi = rq[h * 24 + i];
        float l[24];
        float m = -1e30f;
        #pragma unroll
        for (int j = 0; j < 24; ++j) {
            l[j] = S[b * 2304 + (h * 24 + i) * 24 + j] * rqi * rk[h * 24 + j] * tmp;
            m = fmaxf(m, l[j]);
        }
        float ssum = 0.f;
        #pragma unroll
        for (int j = 0; j < 24; ++j) { l[j] = expf(l[j] - m); ssum += l[j]; }
        const float inv = 1.f / ssum;
        #pragma unroll
        for (int j = 0; j < 24; ++j) att[(h * 24 + i) * 24 + j] = l[j] * inv;
    }
    __syncthreads();

    // M[oc][dg] = sum_i w_out[oc][h*24+i] * att[h][i][dg%24], h = dg/24
    for (int k = 0; k < 36; ++k) {
        const int id = k * 256 + tid;     // 0..9215
        const int dg = id / 96, oc = id % 96;
        const int h = dg / 24, d24 = dg % 24;
        float s = 0.f;
        #pragma unroll
        for (int i = 0; i < 24; ++i) {
            s += w_out[oc * 96 + h * 24 + i] * att[(h * 24 + i) * 24 + d24];
        }
        const u16 hh = f2bf(s);
        mhi[b * 9216 + oc * 96 + dg] = hh;
        mlo[b * 9216 + oc * 96 + dg] = f2bf(s - bf2f(hh));
    }
}

// K4: out = M @ v via MFMA. grid (512 px-tiles, 4 b), 256 thr.
__global__ __launch_bounds__(256) void k_out_mfma(
    const u16* __restrict__ v, const u16* __restrict__ mhi, const u16* __restrict__ mlo,
    float* __restrict__ out)
{
    const int b = blockIdx.y;
    const int px0 = blockIdx.x * 128;
    const int tid = threadIdx.x;
    __shared__ __align__(16) u16 xt[16384];

    const u16* vb = v + (size_t)b * 96 * HWn;
    const u16* mh = mhi + b * 9216;
    const u16* ml = mlo + b * 9216;

    const int icq = tid >> 4;
    const int pxs = (tid & 15) * 8;
    #pragma unroll 1
    for (int p = 0; p < 6; ++p) {
        const int dg = p * 16 + icq;
        const uint4 u = *reinterpret_cast<const uint4*>(vb + (size_t)dg * HWn + px0 + pxs);
        const u32 w[4] = {u.x, u.y, u.z, u.w};
        const int icb = dg >> 3, icl = dg & 7;
        #pragma unroll
        for (int j = 0; j < 8; ++j) {
            xt[xoff(pxs + j, icb) + icl] = (u16)(w[j >> 1] >> ((j & 1) * 16));
        }
    }
    __syncthreads();

    const int lane = tid & 63;
    const int wv = tid >> 6;
    const int oc0 = (wv >> 1) * 48;
    const int pxw = (wv & 1) * 64;
    const int lr = lane & 15, lg = lane >> 4;

    f32x4 acc[3][4];
    #pragma unroll
    for (int m = 0; m < 3; ++m)
        #pragma unroll
        for (int n = 0; n < 4; ++n)
            acc[m][n] = (f32x4){0.f, 0.f, 0.f, 0.f};

    #pragma unroll 1
    for (int s = 0; s < 6; ++s) {
        const int pass = s / 3, kt = s - pass * 3;
        const int kb = kt * 32;
        const u16* wsrc = pass ? ml : mh;
        bf16x8 A[3], B[4];
        #pragma unroll
        for (int m = 0; m < 3; ++m) {
            const int row = oc0 + m * 16 + lr;
            A[m] = *(const bf16x8*)(wsrc + row * 96 + kb + lg * 8);
        }
        #pragma unroll
        for (int n = 0; n < 4; ++n) {
            const int px = pxw + n * 16 + lr;
            B[n] = *(const bf16x8*)(xt + xoff(px, (kb >> 3) + lg));
        }
        #pragma unroll
        for (int m = 0; m < 3; ++m)
            #pragma unroll
            for (int n = 0; n < 4; ++n)
                acc[m][n] = __builtin_amdgcn_mfma_f32_16x16x32_bf16(A[m], B[n], acc[m][n], 0, 0, 0);
    }

    #pragma unroll
    for (int m = 0; m < 3; ++m) {
        #pragma unroll
        for (int i = 0; i < 4; ++i) {
            const int oc = oc0 + m * 16 + lg * 4 + i;
            float* drow = out + ((size_t)(b * 96 + oc)) * HWn + px0;
            #pragma unroll
            for (int n = 0; n < 4; ++n)
                drow[pxw + n * 16 + lr] = acc[m][n][i];
        }
    }
}

extern "C" void kernel_launch(void* const* d_in, const int* in_sizes, int n_in,
                              void* d_out, int out_size, void* d_ws, size_t ws_size,
                              hipStream_t stream) {
    (void)in_sizes; (void)n_in; (void)out_size; (void)ws_size;
    const float* x      = (const float*)d_in[0];
    const float* ff     = (const float*)d_in[1];
    const float* w_q    = (const float*)d_in[2];
    const float* w_kv   = (const float*)d_in[3];
    const float* w_q_dw = (const float*)d_in[4];
    const float* w_kv_dw= (const float*)d_in[5];
    const float* w_out  = (const float*)d_in[6];
    const float* temp   = (const float*)d_in[7];
    float* out = (float*)d_out;

    char* ws = (char*)d_ws;
    u16* qpre   = (u16*)(ws);                      //  50,331,648 B
    u16* kvpre  = (u16*)(ws + 50331648);           // 100,663,296 B
    u16* vbuf   = (u16*)(ws + 150994944);          //  50,331,648 B
    float* ssq  = (float*)(ws + 201326592);        //       3,072 B
    float* S    = (float*)(ws + 201329664);        //      36,864 B
    u16* whi    = (u16*)(ws + 201366528);          //      55,296 B
    u16* wlo    = (u16*)(ws + 201421824);          //      55,296 B
    u16* mhi    = (u16*)(ws + 201477120);          //      73,728 B
    u16* mlo    = (u16*)(ws + 201550848);          //      73,728 B

    hipMemsetAsync(ssq, 0, 3072 + 36864, stream);

    k_prep_w<<<108, 256, 0, stream>>>(w_q, w_kv, whi, wlo);
    k_conv_mfma<<<dim3(512, 3, 4), 256, 0, stream>>>(ff, x, whi, wlo, qpre, kvpre);
    k_dw_fused<<<dim3(1024), 512, 0, stream>>>(qpre, kvpre, w_q_dw, w_kv_dw, vbuf, ssq, S);
    k_attn_fold<<<4, 256, 0, stream>>>(ssq, S, temp, w_out, mhi, mlo);
    k_out_mfma<<<dim3(512, 4), 256, 0, stream>>>(vbuf, mhi, mlo, out);
}

// Round 4
// 323.023 us; speedup vs baseline: 3.0183x; 1.3786x over previous
//
#include <hip/hip_runtime.h>
#include <hip/hip_bf16.h>

typedef unsigned int u32;
typedef unsigned short u16;

static constexpr int Cn = 96;
static constexpr int HWn = 65536;

typedef __attribute__((ext_vector_type(8))) short bf16x8;
typedef __attribute__((ext_vector_type(4))) float f32x4;

__device__ __forceinline__ float bf2f(u16 u) {
    union { u32 i; float f; } z; z.i = ((u32)u) << 16; return z.f;
}
__device__ __forceinline__ u16 f2bf(float f) {
    __hip_bfloat16 h = __float2bfloat16(f);
    return *reinterpret_cast<u16*>(&h);
}
__device__ __forceinline__ u32 pack2(float a, float b) {
    return ((u32)f2bf(b) << 16) | (u32)f2bf(a);
}
__device__ __forceinline__ float lo2f(u32 u) {
    union { u32 i; float f; } z; z.i = u << 16; return z.f;
}
__device__ __forceinline__ float hi2f(u32 u) {
    union { u32 i; float f; } z; z.i = u & 0xffff0000u; return z.f;
}
__device__ __forceinline__ float sq2bf(u32 a) {
    union { u32 i; float f; } al, ah;
    al.i = a << 16; ah.i = a & 0xffff0000u;
    return fmaf(al.f, al.f, ah.f * ah.f);
}

// Swizzled LDS offset (u16 units) for transposed X tile: [px 0..127][ic 0..95]
__device__ __forceinline__ int xoff(int px, int icb) {
    return px * 128 + (((icb ^ (px & 7) ^ ((px >> 3) & 7))) << 3);
}

// Split conv1x1 weights into bf16 hi/lo, layout [sec*96+oc][ic]
__global__ __launch_bounds__(256) void k_prep_w(
    const float* __restrict__ wq, const float* __restrict__ wkv,
    u16* __restrict__ whi, u16* __restrict__ wlo)
{
    const int i = blockIdx.x * 256 + threadIdx.x;
    if (i >= 288 * 96) return;
    const int row = i / 96, ic = i % 96;
    const float w = (row < 96) ? wq[row * 96 + ic] : wkv[(row - 96) * 96 + ic];
    const u16 h = f2bf(w);
    whi[i] = h;
    wlo[i] = f2bf(w - bf2f(h));
}

// K1: conv1x1 via MFMA. grid (512 px-tiles, 2 sec {q, kv}, 4 b), 256 thr.
// sec==1 stages x once and runs two weight passes (kv0, kv1).
__global__ __launch_bounds__(256) void k_conv_mfma(
    const float* __restrict__ ff, const float* __restrict__ x,
    const u16* __restrict__ whi, const u16* __restrict__ wlo,
    u16* __restrict__ qpre, u16* __restrict__ kvpre)
{
    const int b = blockIdx.z, sec = blockIdx.y;
    const int px0 = blockIdx.x * 128;
    const int tid = threadIdx.x;

    __shared__ __align__(16) u16 xhi[16384];
    __shared__ __align__(16) u16 xlo[16384];

    const float* src = (sec == 0 ? ff : x) + (size_t)b * 96 * HWn;

    const int icq = tid >> 4;
    const int pxs = (tid & 15) * 8;
    #pragma unroll 1
    for (int p = 0; p < 6; ++p) {
        const int ic = p * 16 + icq;
        const float* rp = src + (size_t)ic * HWn + px0 + pxs;
        const float4 va = *reinterpret_cast<const float4*>(rp);
        const float4 vb = *reinterpret_cast<const float4*>(rp + 4);
        const int icb = ic >> 3, icl = ic & 7;
        float e[8] = {va.x, va.y, va.z, va.w, vb.x, vb.y, vb.z, vb.w};
        #pragma unroll
        for (int j = 0; j < 8; ++j) {
            const int o = xoff(pxs + j, icb) + icl;
            const u16 h = f2bf(e[j]);
            xhi[o] = h;
            xlo[o] = f2bf(e[j] - bf2f(h));
        }
    }
    __syncthreads();

    const int lane = tid & 63;
    const int wv = tid >> 6;
    const int oc0 = (wv >> 1) * 48;
    const int pxw = (wv & 1) * 64;
    const int lr = lane & 15, lg = lane >> 4;

    const int npass = (sec == 0) ? 1 : 2;
    #pragma unroll 1
    for (int kvs = 0; kvs < npass; ++kvs) {
        const int wrow = (sec == 0) ? 0 : (96 + kvs * 96);
        const u16* wh = whi + wrow * 96;
        const u16* wl = wlo + wrow * 96;
        u16* dst = (sec == 0) ? (qpre + (size_t)b * 96 * HWn)
                              : (kvpre + (size_t)b * 192 * HWn + (size_t)kvs * 96 * HWn);

        f32x4 acc[3][4];
        #pragma unroll
        for (int m = 0; m < 3; ++m)
            #pragma unroll
            for (int n = 0; n < 4; ++n)
                acc[m][n] = (f32x4){0.f, 0.f, 0.f, 0.f};

        #pragma unroll 1
        for (int s = 0; s < 9; ++s) {
            const int pass = s / 3, kt = s - pass * 3;
            const int kb = kt * 32;
            const u16* wsrc = (pass == 2) ? wl : wh;
            const u16* xsrc = (pass == 1) ? xlo : xhi;
            bf16x8 A[3], B[4];
            #pragma unroll
            for (int m = 0; m < 3; ++m)
                A[m] = *(const bf16x8*)(wsrc + (oc0 + m * 16 + lr) * 96 + kb + lg * 8);
            #pragma unroll
            for (int n = 0; n < 4; ++n)
                B[n] = *(const bf16x8*)(xsrc + xoff(pxw + n * 16 + lr, (kb >> 3) + lg));
            #pragma unroll
            for (int m = 0; m < 3; ++m)
                #pragma unroll
                for (int n = 0; n < 4; ++n)
                    acc[m][n] = __builtin_amdgcn_mfma_f32_16x16x32_bf16(A[m], B[n], acc[m][n], 0, 0, 0);
        }

        #pragma unroll
        for (int m = 0; m < 3; ++m) {
            #pragma unroll
            for (int i = 0; i < 4; ++i) {
                const int oc = oc0 + m * 16 + lg * 4 + i;
                u16* drow = dst + (size_t)oc * HWn + px0;
                #pragma unroll
                for (int n = 0; n < 4; ++n)
                    drow[pxw + n * 16 + lr] = f2bf(acc[m][n][i]);
            }
        }
    }
}

// K2: fused depthwise 3x3 + reductions. 128-px half-row tiles, 512 thr,
// LDS 52 KB (3 blocks/CU). Horizontal halo via __shfl; S via MFMA.
__global__ __launch_bounds__(512) void k_dw_fused(
    const u16* __restrict__ qpre, const u16* __restrict__ kvpre,
    const float* __restrict__ wqdw, const float* __restrict__ wkvdw,
    u16* __restrict__ vout, float* __restrict__ ssq, float* __restrict__ Sg)
{
    const int bid = blockIdx.x;                  // 0..2047
    const int wg = (bid & 7) * 256 + (bid >> 3); // XCD: contiguous y span per XCD
    const int b = wg >> 9;
    const int rem = wg & 511;
    const int y = rem >> 1;
    const int tx = (rem & 1) * 128;
    const int tid = threadIdx.x;
    const int lane = tid & 63;
    const int chunk = tid & 15;
    const int x0l = chunk * 8;
    const int xg = tx + x0l;

    __shared__ __align__(16) u16 qs[96][136];
    __shared__ __align__(16) u16 ks[96][136];

    #pragma unroll 1
    for (int it = 0; it < 9; ++it) {
        const int p = it * 32 + (tid >> 4);      // plane 0..287
        const u16* src; const float* wp; int c;
        if (p < 96)       { c = p;       src = qpre  + ((size_t)(b * 96 + c)) * HWn;       wp = wqdw  + c * 9; }
        else if (p < 192) { c = p - 96;  src = kvpre + ((size_t)(b * 192 + c)) * HWn;      wp = wkvdw + c * 9; }
        else              { c = p - 192; src = kvpre + ((size_t)(b * 192 + 96 + c)) * HWn; wp = wkvdw + (96 + c) * 9; }

        float a0 = 0.f, a1 = 0.f, a2 = 0.f, a3 = 0.f, a4 = 0.f, a5 = 0.f, a6 = 0.f, a7 = 0.f;

        #pragma unroll
        for (int r = 0; r < 3; ++r) {
            const int ry = y + r - 1;
            if ((unsigned)ry < 256u) {           // block-uniform branch
                const u16* row = src + ry * 256 + xg;
                const uint4 m = *reinterpret_cast<const uint4*>(row);
                const float v1 = lo2f(m.x), v2 = hi2f(m.x);
                const float v3 = lo2f(m.y), v4 = hi2f(m.y);
                const float v5 = lo2f(m.z), v6 = hi2f(m.z);
                const float v7 = lo2f(m.w), v8 = hi2f(m.w);
                const float lv = __shfl(v8, (lane - 1) & 63);
                const float rv = __shfl(v1, (lane + 1) & 63);
                const float v0 = (chunk == 0)  ? ((xg > 0)       ? bf2f(row[-1]) : 0.f) : lv;
                const float v9 = (chunk == 15) ? ((xg + 8 < 256) ? bf2f(row[8])  : 0.f) : rv;
                const float w0 = wp[r * 3 + 0], w1 = wp[r * 3 + 1], w2 = wp[r * 3 + 2];
                a0 = fmaf(w0, v0, fmaf(w1, v1, fmaf(w2, v2, a0)));
                a1 = fmaf(w0, v1, fmaf(w1, v2, fmaf(w2, v3, a1)));
                a2 = fmaf(w0, v2, fmaf(w1, v3, fmaf(w2, v4, a2)));
                a3 = fmaf(w0, v3, fmaf(w1, v4, fmaf(w2, v5, a3)));
                a4 = fmaf(w0, v4, fmaf(w1, v5, fmaf(w2, v6, a4)));
                a5 = fmaf(w0, v5, fmaf(w1, v6, fmaf(w2, v7, a5)));
                a6 = fmaf(w0, v6, fmaf(w1, v7, fmaf(w2, v8, a6)));
                a7 = fmaf(w0, v7, fmaf(w1, v8, fmaf(w2, v9, a7)));
            }
        }

        const uint4 o = make_uint4(pack2(a0, a1), pack2(a2, a3), pack2(a4, a5), pack2(a6, a7));
        if (p < 96) {
            *reinterpret_cast<uint4*>(&qs[c][x0l]) = o;
        } else if (p < 192) {
            *reinterpret_cast<uint4*>(&ks[c][x0l]) = o;
        } else {
            *reinterpret_cast<uint4*>(vout + ((size_t)(b * 96 + c)) * HWn + y * 256 + xg) = o;
        }
    }
    __syncthreads();

    // ssq: 192 rows x 2 halves (64 px) = 384 tasks
    if (tid < 384) {
        const int half = tid >= 192;
        const int r = tid - half * 192;
        const uint4* rr = reinterpret_cast<const uint4*>(
            (r < 96 ? &qs[r][0] : &ks[r - 96][0]) + half * 64);
        float s = 0.f;
        #pragma unroll
        for (int pch = 0; pch < 8; ++pch) {
            const uint4 a = rr[pch];
            s += sq2bf(a.x) + sq2bf(a.y) + sq2bf(a.z) + sq2bf(a.w);
        }
        atomicAdd(ssq + b * 192 + r, s);
    }

    // S via MFMA: wave w -> head h = w&3, row-tile mt = w>>2.
    {
        const int w = tid >> 6;
        const int h = w & 3, mt = w >> 2;
        const int lr = lane & 15, lg = lane >> 4;
        const int ar = h * 24 + min(mt * 16 + lr, 23);   // clamp-dup, discard on store
        f32x4 acc[2];
        acc[0] = (f32x4){0.f, 0.f, 0.f, 0.f};
        acc[1] = (f32x4){0.f, 0.f, 0.f, 0.f};
        #pragma unroll
        for (int ks4 = 0; ks4 < 4; ++ks4) {
            const bf16x8 A = *(const bf16x8*)(&qs[ar][ks4 * 32 + lg * 8]);
            #pragma unroll
            for (int nt = 0; nt < 2; ++nt) {
                const int bc = h * 24 + min(nt * 16 + lr, 23);
                const bf16x8 B = *(const bf16x8*)(&ks[bc][ks4 * 32 + lg * 8]);
                acc[nt] = __builtin_amdgcn_mfma_f32_16x16x32_bf16(A, B, acc[nt], 0, 0, 0);
            }
        }
        #pragma unroll
        for (int nt = 0; nt < 2; ++nt) {
            const int col = nt * 16 + lr;
            #pragma unroll
            for (int reg = 0; reg < 4; ++reg) {
                const int row24 = mt * 16 + lg * 4 + reg;
                if (row24 < 24 && col < 24)
                    atomicAdd(Sg + b * 2304 + h * 576 + row24 * 24 + col, acc[nt][reg]);
            }
        }
    }
}

// K3: normalize, softmax, fold w_out with block-diag attn -> Mhi/Mlo [oc][dg] bf16
__global__ __launch_bounds__(256) void k_attn_fold(
    const float* __restrict__ ssq, const float* __restrict__ S,
    const float* __restrict__ temp, const float* __restrict__ w_out,
    u16* __restrict__ mhi, u16* __restrict__ mlo)
{
    const int b = blockIdx.x;
    const int tid = threadIdx.x;
    __shared__ float rq[96], rk[96], att[2304];

    if (tid < 96) {
        rq[tid] = 1.f / fmaxf(sqrtf(ssq[b * 192 + tid]), 1e-12f);
    } else if (tid < 192) {
        const int c = tid - 96;
        rk[c] = 1.f / fmaxf(sqrtf(ssq[b * 192 + 96 + c]), 1e-12f);
    }
    __syncthreads();

    if (tid < 96) {
        const int h = tid / 24, i = tid % 24;
        const float tmp = temp[h];
        const float rqi = rq[h * 24 + i];
        float l[24];
        float m = -1e30f;
        #pragma unroll
        for (int j = 0; j < 24; ++j) {
            l[j] = S[b * 2304 + (h * 24 + i) * 24 + j] * rqi * rk[h * 24 + j] * tmp;
            m = fmaxf(m, l[j]);
        }
        float ssum = 0.f;
        #pragma unroll
        for (int j = 0; j < 24; ++j) { l[j] = expf(l[j] - m); ssum += l[j]; }
        const float inv = 1.f / ssum;
        #pragma unroll
        for (int j = 0; j < 24; ++j) att[(h * 24 + i) * 24 + j] = l[j] * inv;
    }
    __syncthreads();

    for (int k = 0; k < 36; ++k) {
        const int id = k * 256 + tid;
        const int dg = id / 96, oc = id % 96;
        const int h = dg / 24, d24 = dg % 24;
        float s = 0.f;
        #pragma unroll
        for (int i = 0; i < 24; ++i) {
            s += w_out[oc * 96 + h * 24 + i] * att[(h * 24 + i) * 24 + d24];
        }
        const u16 hh = f2bf(s);
        mhi[b * 9216 + oc * 96 + dg] = hh;
        mlo[b * 9216 + oc * 96 + dg] = f2bf(s - bf2f(hh));
    }
}

// K4: out = M @ v via MFMA. grid (512 px-tiles, 4 b), 256 thr.
__global__ __launch_bounds__(256) void k_out_mfma(
    const u16* __restrict__ v, const u16* __restrict__ mhi, const u16* __restrict__ mlo,
    float* __restrict__ out)
{
    const int b = blockIdx.y;
    const int px0 = blockIdx.x * 128;
    const int tid = threadIdx.x;
    __shared__ __align__(16) u16 xt[16384];

    const u16* vb = v + (size_t)b * 96 * HWn;
    const u16* mh = mhi + b * 9216;
    const u16* ml = mlo + b * 9216;

    const int icq = tid >> 4;
    const int pxs = (tid & 15) * 8;
    #pragma unroll 1
    for (int p = 0; p < 6; ++p) {
        const int dg = p * 16 + icq;
        const uint4 u = *reinterpret_cast<const uint4*>(vb + (size_t)dg * HWn + px0 + pxs);
        const u32 w[4] = {u.x, u.y, u.z, u.w};
        const int icb = dg >> 3, icl = dg & 7;
        #pragma unroll
        for (int j = 0; j < 8; ++j) {
            xt[xoff(pxs + j, icb) + icl] = (u16)(w[j >> 1] >> ((j & 1) * 16));
        }
    }
    __syncthreads();

    const int lane = tid & 63;
    const int wv = tid >> 6;
    const int oc0 = (wv >> 1) * 48;
    const int pxw = (wv & 1) * 64;
    const int lr = lane & 15, lg = lane >> 4;

    f32x4 acc[3][4];
    #pragma unroll
    for (int m = 0; m < 3; ++m)
        #pragma unroll
        for (int n = 0; n < 4; ++n)
            acc[m][n] = (f32x4){0.f, 0.f, 0.f, 0.f};

    #pragma unroll 1
    for (int s = 0; s < 6; ++s) {
        const int pass = s / 3, kt = s - pass * 3;
        const int kb = kt * 32;
        const u16* wsrc = pass ? ml : mh;
        bf16x8 A[3], B[4];
        #pragma unroll
        for (int m = 0; m < 3; ++m)
            A[m] = *(const bf16x8*)(wsrc + (oc0 + m * 16 + lr) * 96 + kb + lg * 8);
        #pragma unroll
        for (int n = 0; n < 4; ++n)
            B[n] = *(const bf16x8*)(xt + xoff(pxw + n * 16 + lr, (kb >> 3) + lg));
        #pragma unroll
        for (int m = 0; m < 3; ++m)
            #pragma unroll
            for (int n = 0; n < 4; ++n)
                acc[m][n] = __builtin_amdgcn_mfma_f32_16x16x32_bf16(A[m], B[n], acc[m][n], 0, 0, 0);
    }

    #pragma unroll
    for (int m = 0; m < 3; ++m) {
        #pragma unroll
        for (int i = 0; i < 4; ++i) {
            const int oc = oc0 + m * 16 + lg * 4 + i;
            float* drow = out + ((size_t)(b * 96 + oc)) * HWn + px0;
            #pragma unroll
            for (int n = 0; n < 4; ++n)
                drow[pxw + n * 16 + lr] = acc[m][n][i];
        }
    }
}

extern "C" void kernel_launch(void* const* d_in, const int* in_sizes, int n_in,
                              void* d_out, int out_size, void* d_ws, size_t ws_size,
                              hipStream_t stream) {
    (void)in_sizes; (void)n_in; (void)out_size; (void)ws_size;
    const float* x      = (const float*)d_in[0];
    const float* ff     = (const float*)d_in[1];
    const float* w_q    = (const float*)d_in[2];
    const float* w_kv   = (const float*)d_in[3];
    const float* w_q_dw = (const float*)d_in[4];
    const float* w_kv_dw= (const float*)d_in[5];
    const float* w_out  = (const float*)d_in[6];
    const float* temp   = (const float*)d_in[7];
    float* out = (float*)d_out;

    char* ws = (char*)d_ws;
    u16* qpre   = (u16*)(ws);                      //  50,331,648 B
    u16* kvpre  = (u16*)(ws + 50331648);           // 100,663,296 B
    u16* vbuf   = (u16*)(ws + 150994944);          //  50,331,648 B
    float* ssq  = (float*)(ws + 201326592);        //       3,072 B
    float* S    = (float*)(ws + 201329664);        //      36,864 B
    u16* whi    = (u16*)(ws + 201366528);          //      55,296 B
    u16* wlo    = (u16*)(ws + 201421824);          //      55,296 B
    u16* mhi    = (u16*)(ws + 201477120);          //      73,728 B
    u16* mlo    = (u16*)(ws + 201550848);          //      73,728 B

    hipMemsetAsync(ssq, 0, 3072 + 36864, stream);

    k_prep_w<<<108, 256, 0, stream>>>(w_q, w_kv, whi, wlo);
    k_conv_mfma<<<dim3(512, 2, 4), 256, 0, stream>>>(ff, x, whi, wlo, qpre, kvpre);
    k_dw_fused<<<dim3(2048), 512, 0, stream>>>(qpre, kvpre, w_q_dw, w_kv_dw, vbuf, ssq, S);
    k_attn_fold<<<4, 256, 0, stream>>>(ssq, S, temp, w_out, mhi, mlo);
    k_out_mfma<<<dim3(512, 4), 256, 0, stream>>>(vbuf, mhi, mlo, out);
}